// Round 7
// baseline (308.611 us; speedup 1.0000x reference)
//
#include <hip/hip_runtime.h>
#include <stdint.h>

#define N_ROWS 8192
#define D_DIM  1024
#define BK     64
#define NT     (D_DIM / BK)    // 16 K-tiles

typedef __attribute__((ext_vector_type(8))) __bf16 bf16x8;
typedef __attribute__((ext_vector_type(4))) float  f32x4;
typedef __attribute__((address_space(3))) short*  lds_sp;

#define GLD16(gptr, lptr) __builtin_amdgcn_global_load_lds( \
    (const __attribute__((address_space(1))) void*)(gptr),  \
    (__attribute__((address_space(3))) void*)(lptr), 16, 0, 0)

// Opaque LDS read: backend waitcnt pass can't see it -> no auto waits.
#define DSR(dst, addr, OFFSTR) \
    asm volatile("ds_read_b128 %0, %1 offset:" OFFSTR : "=v"(dst) : "v"(addr))

// ---- fragment reads (12 / 8 / 4 per phase; addresses precomputed) ----
#define READ_A03(P) \
    DSR(A0[0], aA0[P], "0");    DSR(A0[1], aA0[P], "2048"); \
    DSR(A0[2], aA0[P], "4096"); DSR(A0[3], aA0[P], "6144"); \
    DSR(A1[0], aA1[P], "0");    DSR(A1[1], aA1[P], "2048"); \
    DSR(A1[2], aA1[P], "4096"); DSR(A1[3], aA1[P], "6144")
#define READ_A47(P) \
    DSR(A2[0], aA0[P], "8192");  DSR(A2[1], aA0[P], "10240"); \
    DSR(A2[2], aA0[P], "12288"); DSR(A2[3], aA0[P], "14336"); \
    DSR(A3[0], aA1[P], "8192");  DSR(A3[1], aA1[P], "10240"); \
    DSR(A3[2], aA1[P], "12288"); DSR(A3[3], aA1[P], "14336")
#define READ_B01(P) \
    DSR(B0[0], aB0[P], "0"); DSR(B0[1], aB0[P], "2048"); \
    DSR(B1[0], aB1[P], "0"); DSR(B1[1], aB1[P], "2048")
#define READ_B23(P) \
    DSR(B2[0], aB0[P], "4096"); DSR(B2[1], aB0[P], "6144"); \
    DSR(B3[0], aB1[P], "4096"); DSR(B3[1], aB1[P], "6144")

// ---- staging: one half-tile (128 rows x 64 cols), 2 loads/thread ----
#define STAGE_A(PAR, H, KB) \
    GLD16(pA + (H)*128*D_DIM + (KB),              SM + (PAR)*16384 + (H)*8192 + tid*8); \
    GLD16(pA + (H)*128*D_DIM + 64*D_DIM + (KB),   SM + (PAR)*16384 + (H)*8192 + 4096 + tid*8)
#define STAGE_B(PAR, H, KB) \
    GLD16(pB + (H)*128*D_DIM + (KB),              SM + 32768 + (PAR)*16384 + (H)*8192 + tid*8); \
    GLD16(pB + (H)*128*D_DIM + 64*D_DIM + (KB),   SM + 32768 + (PAR)*16384 + (H)*8192 + 4096 + tid*8)

// ---- 16-MFMA quadrant: (4 fr) x (2 fc) x (kk0,kk1) ----
#define MF16(AA0, AA1, BB0, BB1, RO, CO)                                      \
    _Pragma("unroll")                                                         \
    for (int fr_ = 0; fr_ < 4; ++fr_) {                                       \
        _Pragma("unroll")                                                     \
        for (int fc_ = 0; fc_ < 2; ++fc_) {                                   \
            acc[(RO)+fr_][(CO)+fc_] = __builtin_amdgcn_mfma_f32_16x16x32_bf16(\
                AA0[fr_], BB0[fc_], acc[(RO)+fr_][(CO)+fc_], 0, 0, 0);        \
            acc[(RO)+fr_][(CO)+fc_] = __builtin_amdgcn_mfma_f32_16x16x32_bf16(\
                AA1[fr_], BB1[fc_], acc[(RO)+fr_][(CO)+fc_], 0, 0, 0);        \
        }                                                                     \
    }

#define PH_MID(LGKM) \
    __builtin_amdgcn_s_barrier(); \
    asm volatile("s_waitcnt lgkmcnt(" #LGKM ")" ::: "memory"); \
    __builtin_amdgcn_sched_barrier(0); \
    __builtin_amdgcn_s_setprio(1)
#define PH_END() \
    __builtin_amdgcn_s_setprio(0); \
    __builtin_amdgcn_sched_barrier(0); \
    __builtin_amdgcn_s_barrier()
#define PH_END_VM(N) \
    __builtin_amdgcn_s_setprio(0); \
    __builtin_amdgcn_sched_barrier(0); \
    asm volatile("s_waitcnt vmcnt(" #N ")" ::: "memory"); \
    __builtin_amdgcn_s_barrier()

// One full K-tile (parity P, other-parity Q): 4 phases.
// Reads are ONE PHASE AHEAD of the MFMA that consumes them (counted lgkm).
// Stages: P0/P1 -> B(t+1) halves; P2/P3 -> A(t+2) halves.
// ONE counted vmcnt(2) per tile at P2-end (ledger: lead-6 half-tiles).
#define TILE_FULL(P, Q, KB1, KB2)                        \
    /* P0: MFMA r0c0; read A47(t) */                     \
    READ_A47(P);                                         \
    STAGE_B(Q, 0, KB1);                                  \
    PH_MID(8);                                           \
    MF16(A0, A1, B0, B1, 0, 0);                          \
    PH_END();                                            \
    /* P1: MFMA r1c0; read B23(t) */                     \
    READ_B23(P);                                         \
    STAGE_B(Q, 1, KB1);                                  \
    PH_MID(4);                                           \
    MF16(A2, A3, B0, B1, 4, 0);                          \
    PH_END();                                            \
    /* P2: MFMA r0c1; no reads; boundary vmcnt */        \
    STAGE_A(P, 0, KB2);                                  \
    PH_MID(0);                                           \
    MF16(A0, A1, B2, B3, 0, 2);                          \
    PH_END_VM(2);                                        \
    /* P3: MFMA r1c1; read A03/B01 of tile t+1 */        \
    READ_A03(Q); READ_B01(Q);                            \
    STAGE_A(P, 1, KB2);                                  \
    PH_MID(12);                                          \
    MF16(A2, A3, B2, B3, 4, 2);                          \
    PH_END()

__device__ __forceinline__ unsigned short f2bf(float v) {
    unsigned int u = __float_as_uint(v);
    u += 0x7fffu + ((u >> 16) & 1u);   // RNE
    return (unsigned short)(u >> 16);
}

// Fused: img -> bf16 (pre-scaled by logit_scale*log2e), txt -> bf16,
// exact fp32 diag, zero-init of row/col accumulators.
__global__ void preprocess_kernel(const float* __restrict__ img,
                                  const float* __restrict__ txt,
                                  const float* __restrict__ scale_p,
                                  short* __restrict__ imgbf,
                                  short* __restrict__ txtbf,
                                  float* __restrict__ diag,
                                  float* __restrict__ row_sum,
                                  float* __restrict__ col_sum) {
    const int row = blockIdx.x;
    const int tid = threadIdx.x;
    const float sc = *scale_p;
    const float f  = sc * 1.44269504088896340736f;

    const float4 x = ((const float4*)(img + (size_t)row * D_DIM))[tid];
    const float4 y = ((const float4*)(txt + (size_t)row * D_DIM))[tid];

    short4 oi, ot;
    oi.x = (short)f2bf(x.x * f); oi.y = (short)f2bf(x.y * f);
    oi.z = (short)f2bf(x.z * f); oi.w = (short)f2bf(x.w * f);
    ot.x = (short)f2bf(y.x);     ot.y = (short)f2bf(y.y);
    ot.z = (short)f2bf(y.z);     ot.w = (short)f2bf(y.w);
    ((short4*)(imgbf + (size_t)row * D_DIM))[tid] = oi;
    ((short4*)(txtbf + (size_t)row * D_DIM))[tid] = ot;

    float s = x.x * y.x + x.y * y.y + x.z * y.z + x.w * y.w;
#pragma unroll
    for (int m = 1; m < 64; m <<= 1) s += __shfl_xor(s, m);
    __shared__ float ws[4];
    if ((tid & 63) == 0) ws[tid >> 6] = s;
    __syncthreads();
    if (tid == 0) {
        diag[row]    = (ws[0] + ws[1] + ws[2] + ws[3]) * sc;
        row_sum[row] = 0.f;
        col_sum[row] = 0.f;
    }
}

// 256x256 tile, 8 waves (2M x 4N), BK=64, half-tile-ring LDS (128 KiB),
// faithful 8-phase cadence with cross-phase read lookahead.
__global__ __launch_bounds__(512, 2)
void gemm_exp_kernel(const short* __restrict__ A,   // img bf16, scaled
                     const short* __restrict__ B,   // txt bf16
                     float* __restrict__ row_sum,
                     float* __restrict__ col_sum) {
    // bytes: A slots [par][half] at par*32768 + half*16384; B at +65536.
    __shared__ __align__(128) short SM[65536];

    const int tid  = threadIdx.x;
    const int lane = tid & 63;
    const int w    = tid >> 6;      // wave 0..7
    const int wm   = w >> 2;        // 0..1
    const int wn   = w & 3;         // 0..3
    const int quad = lane >> 4;
    const int l15  = lane & 15;

    // XCD-bijective block swizzle (1024 blocks, 1024 % 8 == 0)
    const int obid = blockIdx.x;
    const int sw   = (obid & 7) * 128 + (obid >> 3);
    const int ti   = (sw >> 5) * 256;
    const int tj   = (sw & 31) * 256;

    // ---- staging source (pre-swizzled): chunk = i*512 + tid ----
    const int srow = tid >> 3;                  // 0..63
    const int sc   = (tid & 7) ^ (srow & 7);    // inverse of read swizzle
    const short* pA = A + (size_t)(ti + srow) * D_DIM + sc * 8;
    const short* pB = B + (size_t)(tj + srow) * D_DIM + sc * 8;

    // ---- fragment read addresses (bytes); kk1 = kk0 ^ 64 ----
    const int kc0 = quad ^ (l15 & 7);
    const uint32_t lb = (uint32_t)(uintptr_t)(lds_sp)&SM[0];
    uint32_t aA0[2], aA1[2], aB0[2], aB1[2];
    aA0[0] = lb + wm * 16384 + l15 * 128 + kc0 * 16;
    aA0[1] = aA0[0] + 32768;
    aA1[0] = aA0[0] ^ 64;
    aA1[1] = aA0[1] ^ 64;
    aB0[0] = lb + 65536 + (wn >> 1) * 16384 + (wn & 1) * 8192 + l15 * 128 + kc0 * 16;
    aB0[1] = aB0[0] + 32768;
    aB1[0] = aB0[0] ^ 64;
    aB1[1] = aB0[1] ^ 64;

    bf16x8 A0[4], A1[4], A2[4], A3[4];   // A[0-3]/[4-7] x kk0/kk1
    bf16x8 B0[2], B1[2], B2[2], B3[2];   // B[0-1]/[2-3] x kk0/kk1

    f32x4 acc[8][4];
#pragma unroll
    for (int i = 0; i < 8; i++)
#pragma unroll
        for (int j = 0; j < 4; j++) acc[i][j] = (f32x4){0.f, 0.f, 0.f, 0.f};

    // ---- prologue: stage ht0..5 = A(0) both halves, B(0) both, A(1) both ----
    STAGE_A(0, 0, 0);  STAGE_A(0, 1, 0);
    STAGE_B(0, 0, 0);  STAGE_B(0, 1, 0);
    STAGE_A(1, 0, 64); STAGE_A(1, 1, 64);
    asm volatile("s_waitcnt vmcnt(4)" ::: "memory");   // tile 0 landed
    __builtin_amdgcn_s_barrier();
    __builtin_amdgcn_sched_barrier(0);
    READ_A03(0); READ_B01(0);                          // tile-0 P0 operands

    // ---- main loop: tile pairs (t = 2tp, 2tp+1), tiles 0..13 ----
#pragma unroll 1
    for (int tp = 0; tp < 7; ++tp) {
        const int kb1 = (2 * tp + 1) * BK;
        const int kb2 = (2 * tp + 2) * BK;
        const int kb3 = (2 * tp + 3) * BK;
        TILE_FULL(0, 1, kb1, kb2);
        TILE_FULL(1, 0, kb2, kb3);
    }

    // ---- tile 14 (parity 0): stage only B(15); drain at P2 ----
    READ_A47(0); STAGE_B(1, 0, 960);
    PH_MID(8);  MF16(A0, A1, B0, B1, 0, 0); PH_END();
    READ_B23(0); STAGE_B(1, 1, 960);
    PH_MID(4);  MF16(A2, A3, B0, B1, 4, 0); PH_END();
    PH_MID(0);  MF16(A0, A1, B2, B3, 0, 2); PH_END_VM(0);
    READ_A03(1); READ_B01(1);
    PH_MID(12); MF16(A2, A3, B2, B3, 4, 2); PH_END();
    // ---- tile 15 (parity 1): no staging ----
    READ_A47(1);
    PH_MID(8);  MF16(A0, A1, B0, B1, 0, 0); PH_END();
    READ_B23(1);
    PH_MID(4);  MF16(A2, A3, B0, B1, 4, 0); PH_END();
    PH_MID(0);  MF16(A0, A1, B2, B3, 0, 2); PH_END();
    PH_MID(0);  MF16(A2, A3, B2, B3, 4, 2);
    __builtin_amdgcn_s_setprio(0);

    // ---- epilogue: e = 2^acc, row/col reductions ----
#pragma unroll
    for (int fr = 0; fr < 8; ++fr)
#pragma unroll
        for (int fc = 0; fc < 4; ++fc)
#pragma unroll
            for (int r = 0; r < 4; ++r)
                acc[fr][fc][r] = __builtin_amdgcn_exp2f(acc[fr][fc][r]);

    // element (fr,fc,r) = logits[ti + wm*128 + fr*16 + quad*4 + r][tj + wn*64 + fc*16 + l15]
    const int rowbase = ti + wm * 128;
#pragma unroll
    for (int fr = 0; fr < 8; ++fr) {
#pragma unroll
        for (int r = 0; r < 4; ++r) {
            float s = acc[fr][0][r] + acc[fr][1][r] + acc[fr][2][r] + acc[fr][3][r];
            s += __shfl_xor(s, 1);
            s += __shfl_xor(s, 2);
            s += __shfl_xor(s, 4);
            s += __shfl_xor(s, 8);
            if (l15 == 0)
                atomicAdd(&row_sum[rowbase + fr * 16 + quad * 4 + r], s);
        }
    }

    const int colbase = tj + wn * 64;
#pragma unroll
    for (int fc = 0; fc < 4; ++fc) {
        float s = 0.f;
#pragma unroll
        for (int fr = 0; fr < 8; ++fr)
#pragma unroll
            for (int r = 0; r < 4; ++r) s += acc[fr][fc][r];
        s += __shfl_xor(s, 16);
        s += __shfl_xor(s, 32);
        if (quad == 0)
            atomicAdd(&col_sum[colbase + fc * 16 + l15], s);
    }
}

__global__ void finish_kernel(const float* __restrict__ rs, const float* __restrict__ cs,
                              const float* __restrict__ diag, float* __restrict__ out) {
    const int tid  = threadIdx.x;
    const int lane = tid & 63;
    const int w    = tid >> 6;
    float s = 0.f;
    for (int i = tid; i < N_ROWS; i += 256)
        s += logf(rs[i]) + logf(cs[i]) - 2.0f * diag[i];
#pragma unroll
    for (int m = 1; m < 64; m <<= 1) s += __shfl_xor(s, m);
    __shared__ float wsum[4];
    if (lane == 0) wsum[w] = s;
    __syncthreads();
    if (tid == 0)
        out[0] = (wsum[0] + wsum[1] + wsum[2] + wsum[3]) * (0.5f / (float)N_ROWS);
}

extern "C" void kernel_launch(void* const* d_in, const int* in_sizes, int n_in,
                              void* d_out, int out_size, void* d_ws, size_t ws_size,
                              hipStream_t stream) {
    const float* img     = (const float*)d_in[0];
    const float* txt     = (const float*)d_in[1];
    const float* scale_p = (const float*)d_in[2];
    float* out = (float*)d_out;

    char* ws = (char*)d_ws;
    short* imgbf   = (short*)ws;                                  // 16 MB
    short* txtbf   = (short*)(ws + (size_t)16 * 1024 * 1024);     // 16 MB
    float* row_sum = (float*)(ws + (size_t)32 * 1024 * 1024);     // 32 KB
    float* col_sum = row_sum + N_ROWS;                            // 32 KB
    float* diag    = col_sum + N_ROWS;                            // 32 KB

    preprocess_kernel<<<N_ROWS, 256, 0, stream>>>(img, txt, scale_p, imgbf, txtbf,
                                                  diag, row_sum, col_sum);

    gemm_exp_kernel<<<1024, 512, 0, stream>>>(imgbf, txtbf, row_sum, col_sum);

    finish_kernel<<<1, 256, 0, stream>>>(row_sum, col_sum, diag, out);
}